// Round 1
// baseline (390.279 us; speedup 1.0000x reference)
//
#include <hip/hip_runtime.h>

// Problem constants (match reference)
#define N_   8
#define C_   256
#define H_   128
#define W_   128
#define HW_  16384
#define NB_  20
constexpr float TEMP  = 0.5f;
constexpr float IMG_W = 800.0f;
constexpr float IMG_H = 800.0f;

__device__ __forceinline__ float waveReduceSum(float v) {
    v += __shfl_xor(v, 32, 64);
    v += __shfl_xor(v, 16, 64);
    v += __shfl_xor(v, 8, 64);
    v += __shfl_xor(v, 4, 64);
    v += __shfl_xor(v, 2, 64);
    v += __shfl_xor(v, 1, 64);
    return v;
}

// K1: single pass over pT. Per wave: 16 rows. 4-row batched fold (7 shuffles per
// 4 rows, bitwise-identical per-row results to the old 6-shuffle-per-row chain).
// Also: channel sums (LDS + atomicAdd), spatial max (atomicMax on float bits,
// valid since rowsums >= 0), fg mask + bg count (independent of pT, fused here).
// grid: 2048 blocks x 256 threads -> 8192 waves (vs old 2048), 16 waves/CU resident.
__global__ __launch_bounds__(256, 4) void k_stats(const float* __restrict__ pT,
                                                  const float* __restrict__ gt,
                                                  float* __restrict__ chan_sum,
                                                  float* __restrict__ fea_sum,
                                                  unsigned int* __restrict__ smax_bits,
                                                  float* __restrict__ Mfg,
                                                  float* __restrict__ bgcnt) {
    const int n     = blockIdx.x & 7;
    const int chunk = blockIdx.x >> 3;        // 0..255
    const int wave  = threadIdx.x >> 6;
    const int lane  = threadIdx.x & 63;
    const int hwb   = chunk * 64;             // block's 64 rows
    const int hw0   = hwb + wave * 16;        // wave's 16 rows

    float4 cacc = make_float4(0.f, 0.f, 0.f, 0.f);
    float vmax = 0.f;
    #pragma unroll
    for (int g = 0; g < 4; ++g) {
        const int r = hw0 + g * 4;
        float p[4];
        #pragma unroll
        for (int j = 0; j < 4; ++j) {
            const float4 v = *(const float4*)(pT + ((size_t)((r + j) * N_ + n)) * C_ + lane * 4);
            const float ax = fabsf(v.x), ay = fabsf(v.y), az = fabsf(v.z), aw = fabsf(v.w);
            cacc.x += ax; cacc.y += ay; cacc.z += az; cacc.w += aw;
            p[j] = ax + ay + az + aw;
        }
        // fold rows pairwise over xor32 (rows 0/1 and 2/3 share one shuffle each)
        float a01 = (lane & 32) ? p[1] : p[0];
        float b01 = (lane & 32) ? p[0] : p[1];
        const float u01 = a01 + __shfl_xor(b01, 32, 64);
        float a23 = (lane & 32) ? p[3] : p[2];
        float b23 = (lane & 32) ? p[2] : p[3];
        const float u23 = a23 + __shfl_xor(b23, 32, 64);
        // merge the two folded pairs over xor16
        float aq = (lane & 16) ? u23 : u01;
        float bq = (lane & 16) ? u01 : u23;
        float u = aq + __shfl_xor(bq, 16, 64);
        // finish butterfly within 16-lane groups
        u += __shfl_xor(u, 8, 64);
        u += __shfl_xor(u, 4, 64);
        u += __shfl_xor(u, 2, 64);
        u += __shfl_xor(u, 1, 64);
        // quadrant q = lane>>4 holds rowsum of row g*4 + rowmap(q);
        // rowmap: q0->r0, q1->r2, q2->r1, q3->r3
        vmax = fmaxf(vmax, u);
        if ((lane & 15) == 0) {
            const int q = lane >> 4;
            const int row = ((q & 1) << 1) | (q >> 1);
            fea_sum[n * HW_ + r + row] = u;
        }
    }
    // wave max over quadrants -> one atomicMax per wave (rowsums >= 0)
    vmax = fmaxf(vmax, __shfl_xor(vmax, 16, 64));
    vmax = fmaxf(vmax, __shfl_xor(vmax, 32, 64));
    if (lane == 0) atomicMax(&smax_bits[n], __float_as_uint(vmax));

    // channel sums: cross-wave combine in LDS, one atomicAdd per thread
    __shared__ float lds[4][C_];
    ((float4*)lds[wave])[lane] = cacc;
    __syncthreads();
    const int c = threadIdx.x;
    const float cs = lds[0][c] + lds[1][c] + lds[2][c] + lds[3][c];
    atomicAdd(&chan_sum[n * C_ + c], cs);

    // fg mask + bg count for this block's 64 rows (wave 0 only; independent of pT)
    if (threadIdx.x < 64) {
        const int hw = hwb + threadIdx.x;
        const int h = hw >> 7, w = hw & 127;
        float fg = 0.f;
        for (int b = 0; b < NB_; ++b) {
            const float* bx = gt + ((size_t)n * NB_ + b) * 4;
            const float x1 = bx[0], y1 = bx[1], x2 = bx[2], y2 = bx[3];
            const int wmin = (int)floorf(x1 / IMG_W * (float)W_);
            const int wmax = (int)ceilf (x2 / IMG_W * (float)W_);
            const int hmin = (int)floorf(y1 / IMG_H * (float)H_);
            const int hmax = (int)ceilf (y2 / IMG_H * (float)H_);
            if (h >= hmin && h <= hmax && w >= wmin && w <= wmax) {
                const float area = 1.0f / (float)(hmax + 1 - hmin) / (float)(wmax + 1 - wmin);
                fg = fmaxf(fg, area);
            }
        }
        Mfg[n * HW_ + hw] = fg;
        const unsigned long long m = __ballot(fg <= 0.f);
        if (threadIdx.x == 0) atomicAdd(&bgcnt[n], (float)__popcll(m));
    }
}

// K2: spatial softmax denominator, parallelized: 64 blocks (8 per n), each block
// sums exp over 2048 rows -> deterministic partial (no float atomics). Blocks 0..7
// additionally compute the channel softmax B[n,c].
__global__ __launch_bounds__(256) void k_soft(const float* __restrict__ fea_sum,
                                              const float* __restrict__ chan_sum,
                                              const unsigned int* __restrict__ smax_bits,
                                              float* __restrict__ sden_part,
                                              float* __restrict__ B) {
    const int n   = blockIdx.x >> 3;
    const int sub = blockIdx.x & 7;
    const int tid = threadIdx.x;
    __shared__ float red[256];
    const float sm = __uint_as_float(smax_bits[n]) * (1.0f / (C_ * TEMP));
    float acc = 0.f;
    const int base = n * HW_ + sub * 2048;
    #pragma unroll
    for (int k = 0; k < 8; ++k)
        acc += expf(fea_sum[base + k * 256 + tid] * (1.0f / (C_ * TEMP)) - sm);
    red[tid] = acc; __syncthreads();
    for (int s = 128; s > 0; s >>= 1) { if (tid < s) red[tid] += red[tid + s]; __syncthreads(); }
    if (tid == 0) sden_part[blockIdx.x] = red[0];

    if (blockIdx.x >= 8) return;   // uniform per block: no barrier divergence
    __syncthreads();
    // channel softmax for n2 = blockIdx.x
    const int n2 = blockIdx.x;
    const float lc = chan_sum[n2 * C_ + tid] * (1.0f / (HW_ * TEMP));
    red[tid] = lc; __syncthreads();
    for (int s = 128; s > 0; s >>= 1) { if (tid < s) red[tid] = fmaxf(red[tid], red[tid + s]); __syncthreads(); }
    const float cmax = red[0]; __syncthreads();
    const float e = expf(lc - cmax);
    red[tid] = e; __syncthreads();
    for (int s = 128; s > 0; s >>= 1) { if (tid < s) red[tid] += red[tid + s]; __syncthreads(); }
    B[n2 * C_ + tid] = sqrtf((float)C_ * e / red[0]);   // sqrt(C_att)
}

// K3: main weighted-L1 reduction with A computed inline per row (removes the
// former k_A pass). grid: 2048 blocks x 256 threads = 8192 waves, 16 rows/wave.
// sden combined from the 8 deterministic partials in fixed order.
__global__ __launch_bounds__(256, 4) void k_main(const float* __restrict__ pS,
                                                 const float* __restrict__ pT,
                                                 const float* __restrict__ fea_sum,
                                                 const float* __restrict__ Mfg,
                                                 const float* __restrict__ bgcnt,
                                                 const unsigned int* __restrict__ smax_bits,
                                                 const float* __restrict__ sden_part,
                                                 const float* __restrict__ B,
                                                 float* __restrict__ partials) {
    const int wave = threadIdx.x >> 6, lane = threadIdx.x & 63;
    const int wg   = blockIdx.x * 4 + wave;    // 0..8191
    const int n    = wg & 7;
    const int widx = wg >> 3;                  // 0..1023
    const int hw0  = widx * 16;
    const float sm = __uint_as_float(smax_bits[n]) * (1.0f / (C_ * TEMP));
    float sden = 0.f;
    #pragma unroll
    for (int j = 0; j < 8; ++j) sden += sden_part[n * 8 + j];
    const float bgs   = bgcnt[n];
    const float bginv = (bgs > 0.f) ? 1.0f / bgs : 1.0f;
    const float4 B4 = *(const float4*)(B + n * C_ + lane * 4);
    float acc = 0.f;
    #pragma unroll 4
    for (int i = 0; i < 16; ++i) {
        const int hw = hw0 + i;
        const float fs = fea_sum[n * HW_ + hw];
        const float fg = Mfg[n * HW_ + hw];
        const float S_att = (float)HW_ * expf(fs * (1.0f / (C_ * TEMP)) - sm) / sden;
        const float bg = (fg <= 0.f) ? bginv : 0.f;
        const float a_row = sqrtf(S_att) * (sqrtf(fg) + sqrtf(bg)) * (1.0f / (float)HW_);
        const size_t off = ((size_t)(hw * N_ + n)) * C_ + lane * 4;
        const float4 sv = *(const float4*)(pS + off);
        const float4 tv = *(const float4*)(pT + off);
        const float part = fabsf(sv.x - tv.x) * B4.x + fabsf(sv.y - tv.y) * B4.y +
                           fabsf(sv.z - tv.z) * B4.z + fabsf(sv.w - tv.w) * B4.w;
        acc += a_row * part;
    }
    acc = waveReduceSum(acc);
    __shared__ float red[4];
    if (lane == 0) red[wave] = acc;
    __syncthreads();
    if (threadIdx.x == 0) partials[blockIdx.x] = red[0] + red[1] + red[2] + red[3];
}

// K4: deterministic finalize: sum 2048 block partials -> d_out[0]
__global__ __launch_bounds__(256) void k_final(const float* __restrict__ partials,
                                               float* __restrict__ out) {
    float a = 0.f;
    for (int i = threadIdx.x; i < 2048; i += 256) a += partials[i];
    __shared__ float red[256];
    red[threadIdx.x] = a; __syncthreads();
    for (int s = 128; s > 0; s >>= 1) { if (threadIdx.x < s) red[threadIdx.x] += red[threadIdx.x + s]; __syncthreads(); }
    if (threadIdx.x == 0) out[0] = red[0];
}

extern "C" void kernel_launch(void* const* d_in, const int* in_sizes, int n_in,
                              void* d_out, int out_size, void* d_ws, size_t ws_size,
                              hipStream_t stream) {
    const float* pS = (const float*)d_in[0];
    const float* pT = (const float*)d_in[1];
    const float* gt = (const float*)d_in[2];
    float* ws = (float*)d_ws;

    // workspace layout (floats)
    float* chan_sum      = ws;                        // 2048   (atomics -> zero)
    float* bgcnt         = ws + 2048;                 // 8      (atomics -> zero)
    unsigned int* smax   = (unsigned int*)(ws + 2056);// 8      (atomicMax -> zero)
    float* sden_part     = ws + 2064;                 // 64     (written)
    float* fea_sum       = ws + 4096;                 // 131072 (written)
    float* Mfg           = fea_sum + N_ * HW_;        // 131072 (written)
    float* B             = Mfg + N_ * HW_;            // 2048   (written, 16B-aligned)
    float* partials      = B + N_ * C_;               // 2048   (written)

    hipMemsetAsync(ws, 0, 2064 * sizeof(float), stream);

    k_stats<<<2048, 256, 0, stream>>>(pT, gt, chan_sum, fea_sum, smax, Mfg, bgcnt);
    k_soft <<<64,   256, 0, stream>>>(fea_sum, chan_sum, smax, sden_part, B);
    k_main <<<2048, 256, 0, stream>>>(pS, pT, fea_sum, Mfg, bgcnt, smax, sden_part, B, partials);
    k_final<<<1,    256, 0, stream>>>(partials, (float*)d_out);
}

// Round 2
// 315.009 us; speedup vs baseline: 1.2389x; 1.2389x over previous
//
#include <hip/hip_runtime.h>

// Problem constants (match reference)
#define N_   8
#define C_   256
#define H_   128
#define W_   128
#define HW_  16384
#define NB_  20
constexpr float TEMP  = 0.5f;
constexpr float IMG_W = 800.0f;
constexpr float IMG_H = 800.0f;

__device__ __forceinline__ float waveReduceSum(float v) {
    v += __shfl_xor(v, 32, 64);
    v += __shfl_xor(v, 16, 64);
    v += __shfl_xor(v, 8, 64);
    v += __shfl_xor(v, 4, 64);
    v += __shfl_xor(v, 2, 64);
    v += __shfl_xor(v, 1, 64);
    return v;
}

// K1: single pass over pT. Per wave: 16 rows, 4-row batched fold (7 shuffles per
// 4 rows; per-row results bitwise identical to a 6-shuffle butterfly per row).
// NO GLOBAL ATOMICS (round-1 lesson: hot-cacheline RMWs serialized ~100us):
//   - channel partials -> chan_part[n][chunk][c]   (deterministic write)
//   - spatial max      -> smax_part[n][chunk]      (deterministic write)
// grid: 2048 blocks x 256 threads.
__global__ __launch_bounds__(256, 4) void k_stats(const float* __restrict__ pT,
                                                  float* __restrict__ chan_part,
                                                  float* __restrict__ fea_sum,
                                                  float* __restrict__ smax_part) {
    const int n     = blockIdx.x & 7;
    const int chunk = blockIdx.x >> 3;        // 0..255
    const int wave  = threadIdx.x >> 6;
    const int lane  = threadIdx.x & 63;
    const int hw0   = chunk * 64 + wave * 16; // wave's 16 rows

    float4 cacc = make_float4(0.f, 0.f, 0.f, 0.f);
    float vmax = 0.f;
    #pragma unroll
    for (int g = 0; g < 4; ++g) {
        const int r = hw0 + g * 4;
        float p[4];
        #pragma unroll
        for (int j = 0; j < 4; ++j) {
            const float4 v = *(const float4*)(pT + ((size_t)((r + j) * N_ + n)) * C_ + lane * 4);
            const float ax = fabsf(v.x), ay = fabsf(v.y), az = fabsf(v.z), aw = fabsf(v.w);
            cacc.x += ax; cacc.y += ay; cacc.z += az; cacc.w += aw;
            p[j] = ax + ay + az + aw;
        }
        // fold rows pairwise over xor32 (rows 0/1 and 2/3 share one shuffle each)
        float a01 = (lane & 32) ? p[1] : p[0];
        float b01 = (lane & 32) ? p[0] : p[1];
        const float u01 = a01 + __shfl_xor(b01, 32, 64);
        float a23 = (lane & 32) ? p[3] : p[2];
        float b23 = (lane & 32) ? p[2] : p[3];
        const float u23 = a23 + __shfl_xor(b23, 32, 64);
        // merge the two folded pairs over xor16
        float aq = (lane & 16) ? u23 : u01;
        float bq = (lane & 16) ? u01 : u23;
        float u = aq + __shfl_xor(bq, 16, 64);
        // finish butterfly within 16-lane groups
        u += __shfl_xor(u, 8, 64);
        u += __shfl_xor(u, 4, 64);
        u += __shfl_xor(u, 2, 64);
        u += __shfl_xor(u, 1, 64);
        // quadrant q = lane>>4 holds rowsum of row g*4 + rowmap(q);
        // rowmap: q0->r0, q1->r2, q2->r1, q3->r3
        vmax = fmaxf(vmax, u);
        if ((lane & 15) == 0) {
            const int q = lane >> 4;
            const int row = ((q & 1) << 1) | (q >> 1);
            fea_sum[n * HW_ + r + row] = u;
        }
    }
    // wave max over quadrants
    vmax = fmaxf(vmax, __shfl_xor(vmax, 16, 64));
    vmax = fmaxf(vmax, __shfl_xor(vmax, 32, 64));

    __shared__ float lds[4][C_];
    __shared__ float wmax[4];
    if (lane == 0) wmax[wave] = vmax;
    ((float4*)lds[wave])[lane] = cacc;
    __syncthreads();
    const int c = threadIdx.x;
    chan_part[((size_t)(n * 256 + chunk)) * C_ + c] =
        lds[0][c] + lds[1][c] + lds[2][c] + lds[3][c];
    if (threadIdx.x == 0)
        smax_part[n * 256 + chunk] =
            fmaxf(fmaxf(wmax[0], wmax[1]), fmaxf(wmax[2], wmax[3]));
}

// K2: 64 blocks = (n, sub). Each block: spatial max from the 256 chunk maxes;
// deterministic sden partial over its 2048 rows; fg mask + bg count for its
// 2048 rows (box bounds hoisted, no atomics -> bg_part). Blocks with sub==0
// additionally combine channel partials and compute B[n,c] = sqrt(C_att).
__global__ __launch_bounds__(256) void k_soft(const float* __restrict__ fea_sum,
                                              const float* __restrict__ chan_part,
                                              const float* __restrict__ smax_part,
                                              const float* __restrict__ gt,
                                              float* __restrict__ sden_part,  // [N][8]
                                              float* __restrict__ bg_part,    // [N][8]
                                              float* __restrict__ Mfg,        // [N][HW]
                                              float* __restrict__ stats,      // [N] = sm
                                              float* __restrict__ B) {
    const int n   = blockIdx.x >> 3;
    const int sub = blockIdx.x & 7;
    const int tid = threadIdx.x;
    __shared__ float red[256];

    // ---- spatial max over 256 chunk maxes
    red[tid] = smax_part[n * 256 + tid];
    __syncthreads();
    for (int s = 128; s > 0; s >>= 1) { if (tid < s) red[tid] = fmaxf(red[tid], red[tid + s]); __syncthreads(); }
    const float sm = red[0] * (1.0f / (C_ * TEMP));
    __syncthreads();

    // ---- sden partial over rows [sub*2048, +2048)
    float acc = 0.f;
    const int base = n * HW_ + sub * 2048;
    #pragma unroll
    for (int k = 0; k < 8; ++k)
        acc += expf(fea_sum[base + k * 256 + tid] * (1.0f / (C_ * TEMP)) - sm);
    red[tid] = acc; __syncthreads();
    for (int s = 128; s > 0; s >>= 1) { if (tid < s) red[tid] += red[tid + s]; __syncthreads(); }
    if (tid == 0) sden_part[n * 8 + sub] = red[0];
    __syncthreads();

    // ---- fg mask + bg count for rows [sub*2048, +2048); box bounds hoisted
    float fg[8] = {0.f, 0.f, 0.f, 0.f, 0.f, 0.f, 0.f, 0.f};
    for (int b = 0; b < NB_; ++b) {
        const float* bx = gt + ((size_t)n * NB_ + b) * 4;
        const float x1 = bx[0], y1 = bx[1], x2 = bx[2], y2 = bx[3];
        const int wmin = (int)floorf(x1 / IMG_W * (float)W_);
        const int wmax = (int)ceilf (x2 / IMG_W * (float)W_);
        const int hmin = (int)floorf(y1 / IMG_H * (float)H_);
        const int hmax = (int)ceilf (y2 / IMG_H * (float)H_);
        const float area = 1.0f / (float)(hmax + 1 - hmin) / (float)(wmax + 1 - wmin);
        #pragma unroll
        for (int k = 0; k < 8; ++k) {
            const int hw = sub * 2048 + k * 256 + tid;
            const int h = hw >> 7, w = hw & 127;
            if (h >= hmin && h <= hmax && w >= wmin && w <= wmax)
                fg[k] = fmaxf(fg[k], area);
        }
    }
    float bgc = 0.f;
    #pragma unroll
    for (int k = 0; k < 8; ++k) {
        const int hw = sub * 2048 + k * 256 + tid;
        Mfg[n * HW_ + hw] = fg[k];
        bgc += (fg[k] <= 0.f) ? 1.f : 0.f;
    }
    red[tid] = bgc; __syncthreads();
    for (int s = 128; s > 0; s >>= 1) { if (tid < s) red[tid] += red[tid + s]; __syncthreads(); }
    if (tid == 0) bg_part[n * 8 + sub] = red[0];
    if (tid == 0 && sub == 0) stats[n] = sm;

    if (sub != 0) return;   // block-uniform exit
    __syncthreads();

    // ---- channel combine (256 coalesced 1KB reads) + softmax -> B
    float cs = 0.f;
    #pragma unroll 4
    for (int k2 = 0; k2 < 256; ++k2)
        cs += chan_part[((size_t)(n * 256 + k2)) * C_ + tid];
    const float lc = cs * (1.0f / (HW_ * TEMP));
    red[tid] = lc; __syncthreads();
    for (int s = 128; s > 0; s >>= 1) { if (tid < s) red[tid] = fmaxf(red[tid], red[tid + s]); __syncthreads(); }
    const float cmax = red[0]; __syncthreads();
    const float e = expf(lc - cmax);
    red[tid] = e; __syncthreads();
    for (int s = 128; s > 0; s >>= 1) { if (tid < s) red[tid] += red[tid + s]; __syncthreads(); }
    B[n * C_ + tid] = sqrtf((float)C_ * e / red[0]);   // sqrt(C_att)
}

// K3: main weighted-L1 reduction with A computed inline per row.
// grid: 2048 blocks x 256 threads = 8192 waves, 16 rows/wave.
// sden/bg combined from deterministic partials in fixed order.
__global__ __launch_bounds__(256, 4) void k_main(const float* __restrict__ pS,
                                                 const float* __restrict__ pT,
                                                 const float* __restrict__ fea_sum,
                                                 const float* __restrict__ Mfg,
                                                 const float* __restrict__ bg_part,
                                                 const float* __restrict__ stats,
                                                 const float* __restrict__ sden_part,
                                                 const float* __restrict__ B,
                                                 float* __restrict__ partials) {
    const int wave = threadIdx.x >> 6, lane = threadIdx.x & 63;
    const int wg   = blockIdx.x * 4 + wave;    // 0..8191
    const int n    = wg & 7;
    const int widx = wg >> 3;                  // 0..1023
    const int hw0  = widx * 16;
    const float sm = stats[n];
    float sden = 0.f, bgs = 0.f;
    #pragma unroll
    for (int j = 0; j < 8; ++j) { sden += sden_part[n * 8 + j]; bgs += bg_part[n * 8 + j]; }
    const float bginv = (bgs > 0.f) ? 1.0f / bgs : 1.0f;
    const float4 B4 = *(const float4*)(B + n * C_ + lane * 4);
    float acc = 0.f;
    #pragma unroll 4
    for (int i = 0; i < 16; ++i) {
        const int hw = hw0 + i;
        const float fs = fea_sum[n * HW_ + hw];
        const float fg = Mfg[n * HW_ + hw];
        const float S_att = (float)HW_ * expf(fs * (1.0f / (C_ * TEMP)) - sm) / sden;
        const float bg = (fg <= 0.f) ? bginv : 0.f;
        const float a_row = sqrtf(S_att) * (sqrtf(fg) + sqrtf(bg)) * (1.0f / (float)HW_);
        const size_t off = ((size_t)(hw * N_ + n)) * C_ + lane * 4;
        const float4 sv = *(const float4*)(pS + off);
        const float4 tv = *(const float4*)(pT + off);
        const float part = fabsf(sv.x - tv.x) * B4.x + fabsf(sv.y - tv.y) * B4.y +
                           fabsf(sv.z - tv.z) * B4.z + fabsf(sv.w - tv.w) * B4.w;
        acc += a_row * part;
    }
    acc = waveReduceSum(acc);
    __shared__ float red[4];
    if (lane == 0) red[wave] = acc;
    __syncthreads();
    if (threadIdx.x == 0) partials[blockIdx.x] = red[0] + red[1] + red[2] + red[3];
}

// K4: deterministic finalize: sum 2048 block partials -> d_out[0]
__global__ __launch_bounds__(256) void k_final(const float* __restrict__ partials,
                                               float* __restrict__ out) {
    float a = 0.f;
    for (int i = threadIdx.x; i < 2048; i += 256) a += partials[i];
    __shared__ float red[256];
    red[threadIdx.x] = a; __syncthreads();
    for (int s = 128; s > 0; s >>= 1) { if (threadIdx.x < s) red[threadIdx.x] += red[threadIdx.x + s]; __syncthreads(); }
    if (threadIdx.x == 0) out[0] = red[0];
}

extern "C" void kernel_launch(void* const* d_in, const int* in_sizes, int n_in,
                              void* d_out, int out_size, void* d_ws, size_t ws_size,
                              hipStream_t stream) {
    const float* pS = (const float*)d_in[0];
    const float* pT = (const float*)d_in[1];
    const float* gt = (const float*)d_in[2];
    float* ws = (float*)d_ws;

    // workspace layout (floats) — no atomics anywhere, so no memset needed
    float* chan_part = ws;                        // 524288 = N*256*C
    float* smax_part = chan_part + 524288;        // 2048   = N*256
    float* sden_part = smax_part + 2048;          // 64
    float* bg_part   = sden_part + 64;            // 64
    float* stats     = bg_part + 64;              // 8
    float* fea_sum   = ws + 528384;               // 131072 (16B aligned)
    float* Mfg       = fea_sum + N_ * HW_;        // 131072
    float* B         = Mfg + N_ * HW_;            // 2048   (16B aligned)
    float* partials  = B + N_ * C_;               // 2048

    k_stats<<<2048, 256, 0, stream>>>(pT, chan_part, fea_sum, smax_part);
    k_soft <<<64,   256, 0, stream>>>(fea_sum, chan_part, smax_part, gt,
                                      sden_part, bg_part, Mfg, stats, B);
    k_main <<<2048, 256, 0, stream>>>(pS, pT, fea_sum, Mfg, bg_part, stats,
                                      sden_part, B, partials);
    k_final<<<1,    256, 0, stream>>>(partials, (float*)d_out);
}